// Round 10
// baseline (2156.248 us; speedup 1.0000x reference)
//
#include <hip/hip_runtime.h>
#include <hip/hip_bf16.h>

// B=128, T=512, F_IN=128, H=128
#define EPS_ 1e-5f

typedef __attribute__((ext_vector_type(4))) float f32x4;
typedef __attribute__((ext_vector_type(8))) short s16x8;
typedef __attribute__((ext_vector_type(4))) short s16x4;
typedef _Float16 h16x2 __attribute__((ext_vector_type(2)));
typedef _Float16 h16x8 __attribute__((ext_vector_type(8)));
typedef unsigned short u16;

static __device__ __forceinline__ u16 f2bf(float f) {
  __hip_bfloat16 h = __float2bfloat16(f);
  return *reinterpret_cast<u16*>(&h);
}
static __device__ __forceinline__ float bf2f(u16 u) {
  union { float f; unsigned int i; } v; v.i = ((unsigned int)u) << 16; return v.f;
}
static __device__ __forceinline__ float sigf(float x) {
  return __builtin_amdgcn_rcpf(1.f + __expf(-x));
}
static __device__ __forceinline__ float tanhf_(float x) {
  return 2.f * __builtin_amdgcn_rcpf(1.f + __expf(-2.f * x)) - 1.f;
}
static __device__ __forceinline__ f32x4 mfma16(s16x8 a, s16x8 b, f32x4 c) {
  return __builtin_amdgcn_mfma_f32_16x16x32_bf16(a, b, c, 0, 0, 0);
}
static __device__ __forceinline__ float dot2(h16x2 a, h16x2 b, float c) {
#if __has_builtin(__builtin_amdgcn_fdot2)
  return __builtin_amdgcn_fdot2(a, b, c, false);
#else
  return fmaf((float)a[0], (float)b[0], fmaf((float)a[1], (float)b[1], c));
#endif
}

// ---------------- LSTM wih pre-permute: (d,4H,K) f32 -> A-frag bf16 ----------
// dst linear: ((((d*NKS+ks)*4+g)*8+w)*64+lane)*8+e ; r=g*128+w*16+(lane&15),
// k=ks*32+(lane>>4)*8+e  (A-frag mapping of mfma_f32_16x16x32_bf16)
__global__ void convw_kernel(const float* __restrict__ src, u16* __restrict__ dst,
                             int KIN, int ksbits, int total) {
  int i = blockIdx.x * 256 + threadIdx.x;
  if (i >= total) return;
  int e = i & 7;
  int lane = (i >> 3) & 63;
  int w = (i >> 9) & 7;
  int g = (i >> 12) & 3;
  int t2 = i >> 14;
  int ks = t2 & ((1 << ksbits) - 1);
  int d = t2 >> ksbits;
  int r = g * 128 + w * 16 + (lane & 15);
  int k = ks * 32 + (lane >> 4) * 8 + e;
  dst[i] = f2bf(src[((size_t)d * 512 + r) * KIN + k]);
}

// ---------------- whh pre-permute: (d,512,128) f32 -> f16 [d][g][jo][u][8] ---
// dst[i], i = d<<16 | g<<14 | jo<<10 | u<<3 | e ; src[(d*512+g*128+u)*128+jo*8+e]
__global__ void whhd_kernel(const float* __restrict__ src, _Float16* __restrict__ dst,
                            int total) {
  int i = blockIdx.x * 256 + threadIdx.x;
  if (i >= total) return;
  int e = i & 7;
  int u = (i >> 3) & 127;
  int jo = (i >> 10) & 15;
  int g = (i >> 14) & 3;
  int d = i >> 16;
  dst[i] = (_Float16)src[((size_t)d * 512 + g * 128 + u) * 128 + jo * 8 + e];
}

// ---------------- conv weight pre-permute: (O,I,3) f32 -> A-frag bf16 --------
__global__ void convwf_kernel(const float* __restrict__ src, u16* __restrict__ dst,
                              int IC, int NW, int total) {
  int i = blockIdx.x * 256 + threadIdx.x;
  if (i >= total) return;
  int e = i & 7;
  int lane = (i >> 3) & 63;
  int blk = i >> 9;
  int wb = blk % NW;
  int ks = blk / NW;
  int oc = wb * 16 + (lane & 15);
  int k = ks * 32 + (lane >> 4) * 8 + e;
  int tap = k / IC;
  int ic = k - tap * IC;
  dst[i] = f2bf(src[(oc * IC + ic) * 3 + tap]);
}

// ---------------- conv1d (k=3,pad=1) as MFMA GEMM + batch-stat atomics -------
template<int IC, int NW, bool BN>
__global__ __launch_bounds__(512, 1) void convm_kernel(
    const float* __restrict__ xin, const u16* __restrict__ wP,
    const float* __restrict__ bsrc, const float* __restrict__ stats_in,
    const float* __restrict__ g_in, const float* __restrict__ beta_in,
    float* __restrict__ yout, float* __restrict__ stats_out) {
  constexpr int OC = NW * 16;
  constexpr int NKS = (3 * IC) / 32;
  constexpr int ICQ = IC / 32;
  __shared__ u16 xs[66 * IC];
  __shared__ float insc[IC], insh[IC];

  const int tid = threadIdx.x;
  const int wv = tid >> 6, lane = tid & 63, q = lane >> 4, col = lane & 15;
  const int b = blockIdx.x >> 3;
  const int t0 = (blockIdx.x & 7) * 64;
  char* xsb = (char*)xs;

  if constexpr (BN) {
    for (int c = tid; c < IC; c += 512) {
      float s0 = stats_in[2 * c], s1 = stats_in[2 * c + 1];
      float m = s0 * (1.f / 65536.f);
      float v = s1 * (1.f / 65536.f) - m * m;
      float inv = rsqrtf(v + EPS_);
      float a = g_in[c] * inv;
      insc[c] = a; insh[c] = beta_in[c] - m * a;
    }
    __syncthreads();
  }

  for (int n = tid; n < 66 * (IC / 4); n += 512) {
    int r = n / (IC / 4);
    int c4 = (n % (IC / 4)) * 4;
    int t = t0 + r - 1;
    float v0 = 0.f, v1 = 0.f, v2 = 0.f, v3 = 0.f;
    if (t >= 0 && t < 512) {
      f32x4 v = *(const f32x4*)&xin[((size_t)b * 512 + t) * IC + c4];
      v0 = v[0]; v1 = v[1]; v2 = v[2]; v3 = v[3];
      if constexpr (BN) {
        v0 = fmaxf(v0 * insc[c4 + 0] + insh[c4 + 0], 0.f);
        v1 = fmaxf(v1 * insc[c4 + 1] + insh[c4 + 1], 0.f);
        v2 = fmaxf(v2 * insc[c4 + 2] + insh[c4 + 2], 0.f);
        v3 = fmaxf(v3 * insc[c4 + 3] + insh[c4 + 3], 0.f);
      }
    }
    s16x4 u;
    u[0] = (short)f2bf(v0); u[1] = (short)f2bf(v1);
    u[2] = (short)f2bf(v2); u[3] = (short)f2bf(v3);
    int byte = ((r * IC + c4) * 2) ^ ((r & 7) << 4);
    *(s16x4*)(xsb + byte) = u;
  }
  __syncthreads();

  const int wb = (NW == 8) ? wv : (wv & 3);
  const s16x8* wPv = (const s16x8*)wP;
  s16x8 aA[NKS];
#pragma unroll
  for (int ks = 0; ks < NKS; ++ks)
    aA[ks] = wPv[(ks * NW + wb) * 64 + lane];

  f32x4 bias4 = *(const f32x4*)&bsrc[wb * 16 + q * 4];

  constexpr int NSUB = (NW == 8) ? 4 : 2;
  const int st0 = (NW == 8) ? 0 : ((wv >> 2) * 2);

  float ssum0 = 0.f, ssum1 = 0.f, ssum2 = 0.f, ssum3 = 0.f;
  float ssq0 = 0.f, ssq1 = 0.f, ssq2 = 0.f, ssq3 = 0.f;

#pragma unroll
  for (int s = 0; s < NSUB; ++s) {
    const int t_loc = (st0 + s) * 16 + col;
    f32x4 acc = bias4;
#pragma unroll
    for (int ks = 0; ks < NKS; ++ks) {
      const int tap = ks / ICQ;
      const int icb = (ks % ICQ) * 32 + q * 8;
      const int R = t_loc + tap;
      int byte = ((R * IC + icb) * 2) ^ ((R & 7) << 4);
      s16x8 bB = *(const s16x8*)(xsb + byte);
      acc = mfma16(aA[ks], bB, acc);
    }
    *(f32x4*)&yout[((size_t)b * 512 + t0 + t_loc) * OC + wb * 16 + q * 4] = acc;
    ssum0 += acc[0]; ssq0 += acc[0] * acc[0];
    ssum1 += acc[1]; ssq1 += acc[1] * acc[1];
    ssum2 += acc[2]; ssq2 += acc[2] * acc[2];
    ssum3 += acc[3]; ssq3 += acc[3] * acc[3];
  }

#define RED16(S)                                   \
  S += __shfl_xor(S, 1, 64); S += __shfl_xor(S, 2, 64); \
  S += __shfl_xor(S, 4, 64); S += __shfl_xor(S, 8, 64);
  RED16(ssum0) RED16(ssum1) RED16(ssum2) RED16(ssum3)
  RED16(ssq0)  RED16(ssq1)  RED16(ssq2)  RED16(ssq3)
#undef RED16
  if (col == 0) {
    const int ocb = wb * 16 + q * 4;
    atomicAdd(&stats_out[2 * (ocb + 0)], ssum0);
    atomicAdd(&stats_out[2 * (ocb + 0) + 1], ssq0);
    atomicAdd(&stats_out[2 * (ocb + 1)], ssum1);
    atomicAdd(&stats_out[2 * (ocb + 1) + 1], ssq1);
    atomicAdd(&stats_out[2 * (ocb + 2)], ssum2);
    atomicAdd(&stats_out[2 * (ocb + 2) + 1], ssq2);
    atomicAdd(&stats_out[2 * (ocb + 3)], ssum3);
    atomicAdd(&stats_out[2 * (ocb + 3) + 1], ssq3);
  }
}

// ---------------- xg = wih·x + b, batched over all (dir,b,t) -----------------
// Output layout for dot-product LSTM: xg2[(chain*512+t)*512 + u*4 + g],
// chain = dir*128 + sample. Each lane's 16 values (4 units x 4 gates) form one
// contiguous 32B block -> two 16B stores.
template<int KIN, bool BN>
__global__ __launch_bounds__(512, 1) void xg_kernel(
    const void* __restrict__ xin_, const float* __restrict__ stats,
    const float* __restrict__ bng, const float* __restrict__ bnb,
    const u16* __restrict__ wihP, const float* __restrict__ bias,
    u16* __restrict__ xgo) {
  constexpr int NKS = KIN / 32;
  constexpr int XSTR = KIN + 8;
  __shared__ u16 xl[2][16][XSTR];
  __shared__ float sc[128], sh[128];

  const int tid = threadIdx.x;
  const int wv = tid >> 6, lane = tid & 63, q = lane >> 4, col = lane & 15;
  const int bid = blockIdx.x;
  const int dir = bid >> 7, bg = (bid >> 4) & 7, t0 = (bid & 15) * 32;
  const int b0 = bg * 16;
  const int ss = tid >> 5, cc = tid & 31;
  const float* xf = (const float*)xin_;
  const u16* xh = (const u16*)xin_;

  if constexpr (BN) {
    for (int c = tid; c < 128; c += 512) {
      float s0 = stats[2 * c], s1 = stats[2 * c + 1];
      float m = s0 * (1.f / 65536.f);
      float v = s1 * (1.f / 65536.f) - m * m;
      float inv = rsqrtf(v + EPS_);
      float a = bng[c] * inv;
      sc[c] = a; sh[c] = bnb[c] - m * a;
    }
    __syncthreads();
  }

  const s16x8* wihv = (const s16x8*)wihP;
  s16x8 aw[NKS][4];
#pragma unroll
  for (int ks = 0; ks < NKS; ++ks)
#pragma unroll
    for (int g = 0; g < 4; ++g)
      aw[ks][g] = wihv[(((dir * NKS + ks) * 4 + g) * 8 + wv) * 64 + lane];

  f32x4 bias4[4];
#pragma unroll
  for (int g = 0; g < 4; ++g)
    bias4[g] = *(const f32x4*)&bias[dir * 512 + g * 128 + wv * 16 + q * 4];

  if constexpr (KIN == 128) {
    f32x4 v = *(const f32x4*)&xf[((size_t)(b0 + ss) * 512 + t0) * 128 + cc * 4];
    s16x4 u;
#pragma unroll
    for (int j = 0; j < 4; ++j) {
      float xx = v[j];
      if constexpr (BN) xx = fmaxf(xx * sc[cc * 4 + j] + sh[cc * 4 + j], 0.f);
      u[j] = (short)f2bf(xx);
    }
    *(s16x4*)&xl[0][ss][cc * 4] = u;
  } else {
    *(s16x8*)&xl[0][ss][cc * 8] =
        *(const s16x8*)&xh[((size_t)(b0 + ss) * 512 + t0) * 256 + cc * 8];
  }
  __syncthreads();

  const size_t chain = (size_t)dir * 128 + b0 + col;
  int cur = 0;
  for (int i = 0; i < 32; ++i) {
    const int t = t0 + i;
    const int tn = t0 + ((i < 31) ? i + 1 : 31);
    f32x4 xnf; s16x8 xnh;
    if constexpr (KIN == 128)
      xnf = *(const f32x4*)&xf[((size_t)(b0 + ss) * 512 + tn) * 128 + cc * 4];
    else
      xnh = *(const s16x8*)&xh[((size_t)(b0 + ss) * 512 + tn) * 256 + cc * 8];

    s16x8 bx[NKS];
#pragma unroll
    for (int ks = 0; ks < NKS; ++ks)
      bx[ks] = *(const s16x8*)&xl[cur][col][ks * 32 + q * 8];

    f32x4 a0 = bias4[0], a1 = bias4[1], a2 = bias4[2], a3 = bias4[3];
#pragma unroll
    for (int ks = 0; ks < NKS; ++ks) {
      a0 = mfma16(aw[ks][0], bx[ks], a0);
      a1 = mfma16(aw[ks][1], bx[ks], a1);
      a2 = mfma16(aw[ks][2], bx[ks], a2);
      a3 = mfma16(aw[ks][3], bx[ks], a3);
    }

    // interleaved (unit,gate) pack: out[e*4+g] = a_g[e]; 32B/lane contiguous
    u16* op = xgo + (chain * 512 + (size_t)t) * 512 + (size_t)(wv * 16 + q * 4) * 4;
    s16x8 lo, hi;
    lo[0] = (short)f2bf(a0[0]); lo[1] = (short)f2bf(a1[0]);
    lo[2] = (short)f2bf(a2[0]); lo[3] = (short)f2bf(a3[0]);
    lo[4] = (short)f2bf(a0[1]); lo[5] = (short)f2bf(a1[1]);
    lo[6] = (short)f2bf(a2[1]); lo[7] = (short)f2bf(a3[1]);
    hi[0] = (short)f2bf(a0[2]); hi[1] = (short)f2bf(a1[2]);
    hi[2] = (short)f2bf(a2[2]); hi[3] = (short)f2bf(a3[2]);
    hi[4] = (short)f2bf(a0[3]); hi[5] = (short)f2bf(a1[3]);
    hi[6] = (short)f2bf(a2[3]); hi[7] = (short)f2bf(a3[3]);
    *(s16x8*)op = lo;
    *(s16x8*)(op + 8) = hi;

    if constexpr (KIN == 128) {
      s16x4 u;
#pragma unroll
      for (int j = 0; j < 4; ++j) {
        float xx = xnf[j];
        if constexpr (BN) xx = fmaxf(xx * sc[cc * 4 + j] + sh[cc * 4 + j], 0.f);
        u[j] = (short)f2bf(xx);
      }
      *(s16x4*)&xl[cur ^ 1][ss][cc * 4] = u;
    } else {
      *(s16x8*)&xl[cur ^ 1][ss][cc * 8] = xnh;
    }
    __syncthreads();
    cur ^= 1;
  }
}

// ---------------- dot-product recurrent LSTM: 1 block per (dir,sample) ------
// 128 thr (2 waves) = 1 thread per unit. whh resident as f16 h16x2[64] per
// gate (256 VGPRs total); gates = xg2[t] + dot2(whh_row, h[t-1]); h broadcast.
__global__ __launch_bounds__(128, 1) void lstm2_kernel(
    const _Float16* __restrict__ whhD, const u16* __restrict__ xg2,
    u16* __restrict__ hout) {
  __shared__ _Float16 hl[2][128];
  const int u = threadIdx.x;
  const int dir = blockIdx.x >> 7, s = blockIdx.x & 127;
  const size_t chain = (size_t)dir * 128 + s;

  // resident weights: w[g][j] = cols {2j,2j+1} of row (g*128+u), j=0..63
  const h16x8* wv8 = (const h16x8*)whhD;
  h16x2 w0[64], w1[64], w2[64], w3[64];
#pragma unroll
  for (int jo = 0; jo < 16; ++jo) {
    union { h16x8 v; h16x2 h[4]; } t0u, t1u, t2u, t3u;
    t0u.v = wv8[((dir * 4 + 0) * 16 + jo) * 128 + u];
    t1u.v = wv8[((dir * 4 + 1) * 16 + jo) * 128 + u];
    t2u.v = wv8[((dir * 4 + 2) * 16 + jo) * 128 + u];
    t3u.v = wv8[((dir * 4 + 3) * 16 + jo) * 128 + u];
#pragma unroll
    for (int p = 0; p < 4; ++p) {
      w0[jo * 4 + p] = t0u.h[p];
      w1[jo * 4 + p] = t1u.h[p];
      w2[jo * 4 + p] = t2u.h[p];
      w3[jo * 4 + p] = t3u.h[p];
    }
  }

  hl[0][u] = (_Float16)0.f;

  const u16* xp = xg2 + chain * 512 * 512 + (size_t)u * 4;
  const int tstep = dir ? -1 : 1;
  int t = dir ? 511 : 0;

  s16x4 xn = *(const s16x4*)(xp + (size_t)t * 512);

  __syncthreads();   // hl[0] zeros visible

  float c = 0.f;
  int cur = 0;

  for (int it = 0; it < 512; ++it) {
    s16x4 xc = xn;
    const int tn = (it < 511) ? t + tstep : t;
    xn = *(const s16x4*)(xp + (size_t)tn * 512);

    // broadcast h from LDS (same addr all lanes -> conflict-free), split to x2
    h16x2 hh[64];
#pragma unroll
    for (int jo = 0; jo < 16; ++jo) {
      union { h16x8 v; h16x2 h[4]; } th;
      th.v = *(const h16x8*)&hl[cur][jo * 8];
#pragma unroll
      for (int p = 0; p < 4; ++p) hh[jo * 4 + p] = th.h[p];
    }

    float ai = bf2f((u16)xc[0]), af = bf2f((u16)xc[1]);
    float ag = bf2f((u16)xc[2]), ao = bf2f((u16)xc[3]);
    float pi = 0.f, pf = 0.f, pg = 0.f, po = 0.f;  // parity-split partials
#pragma unroll
    for (int j = 0; j < 64; ++j) {
      if (j & 1) {
        pi = dot2(hh[j], w0[j], pi); pf = dot2(hh[j], w1[j], pf);
        pg = dot2(hh[j], w2[j], pg); po = dot2(hh[j], w3[j], po);
      } else {
        ai = dot2(hh[j], w0[j], ai); af = dot2(hh[j], w1[j], af);
        ag = dot2(hh[j], w2[j], ag); ao = dot2(hh[j], w3[j], ao);
      }
    }
    ai += pi; af += pf; ag += pg; ao += po;

    float sI = sigf(ai), sF = sigf(af), tG = tanhf_(ag), sO = sigf(ao);
    c = sF * c + sI * tG;
    float hn = sO * tanhf_(c);

    hout[((size_t)s * 512 + t) * 256 + dir * 128 + u] = f2bf(hn);
    hl[cur ^ 1][u] = (_Float16)hn;

    // barrier with LDS-only drain: hout stores & xg prefetch stay in flight
    asm volatile("s_waitcnt lgkmcnt(0)" ::: "memory");
    __builtin_amdgcn_sched_barrier(0);
    __builtin_amdgcn_s_barrier();
    __builtin_amdgcn_sched_barrier(0);

    cur ^= 1;
    t += tstep;
  }
}

// ---------------- attention pooling: scores -> softmax -> attended -----------
__global__ __launch_bounds__(256) void attn_kernel(
    const u16* __restrict__ h1, const float* __restrict__ attw,
    const float* __restrict__ attb, float* __restrict__ out_attn,
    float* __restrict__ attended) {
  const int b = blockIdx.x;
  const int tid = threadIdx.x;
  const int w = tid >> 6, l = tid & 63;
  __shared__ float sl[512];
  __shared__ float red[256];
  __shared__ float red2[4][256];

  f32x4 wv4 = *(const f32x4*)&attw[l * 4];
  const float ab = attb[0];
  for (int i = 0; i < 128; ++i) {
    int t = w * 128 + i;
    s16x4 v = *(const s16x4*)&h1[((size_t)b * 512 + t) * 256 + l * 4];
    float s = bf2f((u16)v[0]) * wv4[0] + bf2f((u16)v[1]) * wv4[1]
            + bf2f((u16)v[2]) * wv4[2] + bf2f((u16)v[3]) * wv4[3];
#pragma unroll
    for (int m = 32; m > 0; m >>= 1) s += __shfl_xor(s, m, 64);
    if (l == 0) sl[t] = s + ab;
  }
  __syncthreads();

  red[tid] = fmaxf(sl[tid], sl[tid + 256]);
  __syncthreads();
  for (int st = 128; st > 0; st >>= 1) {
    if (tid < st) red[tid] = fmaxf(red[tid], red[tid + st]);
    __syncthreads();
  }
  const float mx = red[0];
  __syncthreads();

  float e0 = __expf(sl[tid] - mx);
  float e1 = __expf(sl[tid + 256] - mx);
  sl[tid] = e0; sl[tid + 256] = e1;
  red[tid] = e0 + e1;
  __syncthreads();
  for (int st = 128; st > 0; st >>= 1) {
    if (tid < st) red[tid] += red[tid + st];
    __syncthreads();
  }
  const float inv = 1.f / red[0];

  out_attn[(size_t)b * 512 + tid] = sl[tid] * inv;
  out_attn[(size_t)b * 512 + tid + 256] = sl[tid + 256] * inv;
  __syncthreads();

  float a0 = 0.f, a1 = 0.f, a2 = 0.f, a3 = 0.f;
  for (int i = 0; i < 128; ++i) {
    int t = w * 128 + i;
    float p = sl[t] * inv;
    s16x4 v = *(const s16x4*)&h1[((size_t)b * 512 + t) * 256 + l * 4];
    a0 += p * bf2f((u16)v[0]); a1 += p * bf2f((u16)v[1]);
    a2 += p * bf2f((u16)v[2]); a3 += p * bf2f((u16)v[3]);
  }
  red2[w][l * 4 + 0] = a0; red2[w][l * 4 + 1] = a1;
  red2[w][l * 4 + 2] = a2; red2[w][l * 4 + 3] = a3;
  __syncthreads();
  attended[b * 256 + tid] =
      red2[0][tid] + red2[1][tid] + red2[2][tid] + red2[3][tid];
}

// ---------------- group-routed decoder MLP (selected expert only) ------------
__global__ __launch_bounds__(64) void dec_kernel(
    const float* __restrict__ attended, const int* __restrict__ labels,
    const float* __restrict__ w1, const float* __restrict__ b1,
    const float* __restrict__ w2, const float* __restrict__ b2,
    const float* __restrict__ w3, const float* __restrict__ b3,
    float* __restrict__ preds) {
  const int b = blockIdx.x;
  const int tid = threadIdx.x;
  const int g = labels[b];
  __shared__ float al[256];
  __shared__ float hl1[64];
  __shared__ float hl2[32];

  for (int i = tid; i < 256; i += 64) al[i] = attended[b * 256 + i];
  __syncthreads();

  {
    const float* wr = &w1[(size_t)(g * 64 + tid) * 256];
    float a = b1[g * 64 + tid];
    for (int d = 0; d < 256; d += 4) {
      f32x4 wv = *(const f32x4*)&wr[d];
      a += al[d] * wv[0] + al[d + 1] * wv[1] + al[d + 2] * wv[2] + al[d + 3] * wv[3];
    }
    hl1[tid] = fmaxf(a, 0.f);
  }
  __syncthreads();
  if (tid < 32) {
    const float* wr = &w2[(size_t)(g * 32 + tid) * 64];
    float a = b2[g * 32 + tid];
    for (int d = 0; d < 64; d += 4) {
      f32x4 wv = *(const f32x4*)&wr[d];
      a += hl1[d] * wv[0] + hl1[d + 1] * wv[1] + hl1[d + 2] * wv[2] + hl1[d + 3] * wv[3];
    }
    hl2[tid] = fmaxf(a, 0.f);
  }
  __syncthreads();
  if (tid < 32) {
    float a = hl2[tid] * w3[g * 32 + tid];
#pragma unroll
    for (int m = 16; m > 0; m >>= 1) a += __shfl_xor(a, m, 32);
    if (tid == 0) preds[b] = a + b3[g];
  }
}

// ---------------- host-side pipeline ----------------------------------------
extern "C" void kernel_launch(void* const* d_in, const int* in_sizes, int n_in,
                              void* d_out, int out_size, void* d_ws, size_t ws_size,
                              hipStream_t stream) {
  const float* x      = (const float*)d_in[0];
  const int*   labels = (const int*)d_in[1];
  const float* conv1w = (const float*)d_in[2];
  const float* conv1b = (const float*)d_in[3];
  const float* bn1g   = (const float*)d_in[4];
  const float* bn1b   = (const float*)d_in[5];
  const float* conv2w = (const float*)d_in[6];
  const float* conv2b = (const float*)d_in[7];
  const float* bn2g   = (const float*)d_in[8];
  const float* bn2b   = (const float*)d_in[9];
  const float* wih0   = (const float*)d_in[10];
  const float* whh0   = (const float*)d_in[11];
  const float* b0     = (const float*)d_in[12];
  const float* wih1   = (const float*)d_in[13];
  const float* whh1   = (const float*)d_in[14];
  const float* b1     = (const float*)d_in[15];
  const float* attw   = (const float*)d_in[16];
  const float* attb   = (const float*)d_in[17];
  const float* dw1    = (const float*)d_in[18];
  const float* db1    = (const float*)d_in[19];
  const float* dw2    = (const float*)d_in[20];
  const float* db2    = (const float*)d_in[21];
  const float* dw3    = (const float*)d_in[22];
  const float* db3    = (const float*)d_in[23];

  char* ws = (char*)d_ws;
  _Float16* whhD0 = (_Float16*)(ws + 0x000000);  // 256KB f16 [d][g][jo][u][8]
  _Float16* whhD1 = (_Float16*)(ws + 0x040000);  // 256KB
  u16*   wih0P = (u16*)  (ws + 0x080000);   // 256KB A-frag bf16
  u16*   wih1P = (u16*)  (ws + 0x0C0000);   // 512KB
  u16*   cw1P  = (u16*)  (ws + 0x140000);   // 48KB conv1 w A-frag
  u16*   cw2P  = (u16*)  (ws + 0x150000);   // 48KB conv2 w A-frag
  float* st1   = (float*)(ws + 0x170000);   // 512B {sum,sumsq} x64
  float* st2   = (float*)(ws + 0x170200);   // 1KB  x128
  float* attd  = (float*)(ws + 0x170600);   // 128KB attended (B,256)
  u16*   h0    = (u16*)  (ws + 0x200000);   // 33.5MB bf16 (B,T,256)
  float* y2    = (float*)(ws + 0x2200000);  // 33.5MB f32 (B,T,128)
  u16*   h1    = (u16*)  (ws + 0x2200000);  // overlays y2 (dead after xg L1)
  u16*   xgb   = (u16*)  (ws + 0x4200000);  // 134.2MB bf16 xg2 (reused L1/L2)
  float* y1    = (float*)(ws + 0x4200000);  // 16MB, overlays xg (dead before)

  float* preds    = (float*)d_out;          // (B,1)
  float* attn_out = (float*)d_out + 128;    // (B,T)

  (void)hipMemsetAsync(ws + 0x170000, 0, 0x600, stream);  // zero stats

  convw_kernel<<<512, 256, 0, stream>>>(wih0, wih0P, 128, 2, 131072);
  convw_kernel<<<1024, 256, 0, stream>>>(wih1, wih1P, 256, 3, 262144);
  whhd_kernel<<<512, 256, 0, stream>>>(whh0, whhD0, 131072);
  whhd_kernel<<<512, 256, 0, stream>>>(whh1, whhD1, 131072);
  convwf_kernel<<<96, 256, 0, stream>>>(conv1w, cw1P, 128, 4, 24576);
  convwf_kernel<<<96, 256, 0, stream>>>(conv2w, cw2P, 64, 8, 24576);

  convm_kernel<128, 4, false><<<1024, 512, 0, stream>>>(
      x, cw1P, conv1b, nullptr, nullptr, nullptr, y1, st1);
  convm_kernel<64, 8, true><<<1024, 512, 0, stream>>>(
      y1, cw2P, conv2b, st1, bn1g, bn1b, y2, st2);

  xg_kernel<128, true><<<256, 512, 0, stream>>>(
      y2, st2, bn2g, bn2b, wih0P, b0, xgb);
  lstm2_kernel<<<256, 128, 0, stream>>>(whhD0, xgb, h0);
  xg_kernel<256, false><<<256, 512, 0, stream>>>(
      h0, nullptr, nullptr, nullptr, wih1P, b1, xgb);
  lstm2_kernel<<<256, 128, 0, stream>>>(whhD1, xgb, h1);

  attn_kernel<<<128, 256, 0, stream>>>(h1, attw, attb, attn_out, attd);
  dec_kernel<<<128, 64, 0, stream>>>(attd, labels, dw1, db1, dw2, db2, dw3, db3, preds);
}